// Round 5
// baseline (76.342 us; speedup 1.0000x reference)
//
#include <hip/hip_runtime.h>
#include <hip/hip_bf16.h>
#include <math.h>

#define TT 577          // real tokens per n
#define TP 640          // padded tokens per n (multiple of 32, >= TT)
#define CCH 768         // channels
#define KR 64           // regions
#define NB 64           // batch

typedef __attribute__((ext_vector_type(8))) short bf16x8;
typedef __attribute__((ext_vector_type(8))) unsigned short ushort8;
typedef __attribute__((ext_vector_type(4))) float f32x4;

static constexpr float EPSF = 1e-12f;

// float -> bf16 bits via HW conversion (RNE); compiler fuses pairs into
// v_cvt_pk_bf16_f32 (m240: scalar cast is the fast path on gfx950).
static __device__ inline unsigned short f2bf(float f) {
    return __bfloat16_as_ushort(__float2bfloat16(f));
}

// ---------------------------------------------------------------------------
// Kernel 1: GEMM1 (logits) + token norms + softmax + transposed a' write
// + per-block partial asum. Grid: 64 n x 5 t-blocks of 128 tokens.
// Block 512 thr = 8 waves x 16 tokens. W chunks (128 c) double-buffered in
// LDS (shared by all 8 waves); Abuf + asum partials aliased onto Wl.
// ---------------------------------------------------------------------------
__global__ __launch_bounds__(512) void k_logits(
    const float* __restrict__ grids,
    const float* __restrict__ conv_w,
    const float* __restrict__ conv_b,
    unsigned short* __restrict__ ws_a,
    float* __restrict__ ws_asum)
{
    __shared__ __align__(16) unsigned short Wl[2][KR * 136];   // 2 x 17.0 KB

    const int tid  = threadIdx.x;
    const int lane = tid & 63;
    const int w    = tid >> 6;                 // 0..7
    const int n    = blockIdx.x / 5;
    const int tb   = (blockIdx.x - n * 5) << 7;
    const int t0w  = tb + (w << 4);

    const int lr = lane & 15;
    const int lg = lane >> 4;

    const int tokA = t0w + lr;
    const bool validA = (tokA < TT);
    const float* gsrc = grids + ((size_t)n * TT + tokA) * CCH + (lg << 3);

    float4 wreg[2][2];
    auto load_w = [&](int c0) {
        #pragma unroll
        for (int it = 0; it < 2; ++it) {
            int f = tid + (it << 9);           // [0,1024): 64 kr x 16 c8-units
            int kr = f >> 4, c8 = (f & 15) << 3;
            const float* src = conv_w + (size_t)kr * CCH + c0 + c8;
            wreg[it][0] = *reinterpret_cast<const float4*>(src);
            wreg[it][1] = *reinterpret_cast<const float4*>(src + 4);
        }
    };
    auto store_w = [&](int buf) {
        #pragma unroll
        for (int it = 0; it < 2; ++it) {
            int f = tid + (it << 9);
            int kr = f >> 4, c8 = (f & 15) << 3;
            ushort8 o;
            o[0] = f2bf(wreg[it][0].x); o[1] = f2bf(wreg[it][0].y);
            o[2] = f2bf(wreg[it][0].z); o[3] = f2bf(wreg[it][0].w);
            o[4] = f2bf(wreg[it][1].x); o[5] = f2bf(wreg[it][1].y);
            o[6] = f2bf(wreg[it][1].z); o[7] = f2bf(wreg[it][1].w);
            *reinterpret_cast<ushort8*>(&Wl[buf][kr * 136 + c8]) = o;
        }
    };

    f32x4 acc[4] = {};
    float ss = 0.f;

    load_w(0);
    store_w(0);
    __syncthreads();

    for (int ch = 0; ch < 6; ++ch) {
        if (ch < 5) {
            load_w((ch + 1) << 7);
            store_w((ch + 1) & 1);
        }
        const int c0 = ch << 7;
        const unsigned short* Wb = Wl[ch & 1];

        #pragma unroll
        for (int s = 0; s < 4; ++s) {
            float a8[8];
            if (validA) {
                float4 u0 = *reinterpret_cast<const float4*>(gsrc + c0 + (s << 5));
                float4 u1 = *reinterpret_cast<const float4*>(gsrc + c0 + (s << 5) + 4);
                a8[0]=u0.x; a8[1]=u0.y; a8[2]=u0.z; a8[3]=u0.w;
                a8[4]=u1.x; a8[5]=u1.y; a8[6]=u1.z; a8[7]=u1.w;
            } else {
                #pragma unroll
                for (int j = 0; j < 8; ++j) a8[j] = 0.f;
            }
            bf16x8 afrag;
            #pragma unroll
            for (int j = 0; j < 8; ++j) {
                ss = fmaf(a8[j], a8[j], ss);
                ((unsigned short*)&afrag)[j] = f2bf(a8[j]);
            }
            const int cl = (s << 5) + (lg << 3);
            #pragma unroll
            for (int rt = 0; rt < 4; ++rt) {
                bf16x8 bfrag = *reinterpret_cast<const bf16x8*>(&Wb[(rt*16 + lr)*136 + cl]);
                acc[rt] = __builtin_amdgcn_mfma_f32_16x16x32_bf16(afrag, bfrag, acc[rt], 0, 0, 0);
            }
        }
        __syncthreads();
    }

    // ---- token norm: reduce the 4 lg-groups of the same token ----
    ss += __shfl_xor(ss, 16);
    ss += __shfl_xor(ss, 32);
    const float nrm = sqrtf(ss);
    const float inv = 1.0f / fmaxf(nrm, EPSF);

    // ---- logits + softmax over 64 regions ----
    float b_[4];
    #pragma unroll
    for (int rt = 0; rt < 4; ++rt) b_[rt] = conv_b[rt*16 + lr];

    float invT[4];
    #pragma unroll
    for (int reg = 0; reg < 4; ++reg) invT[reg] = __shfl(inv, (lg << 2) + reg);

    float lgt[4][4], mx[4];
    #pragma unroll
    for (int reg = 0; reg < 4; ++reg) {
        float m = -1e30f;
        #pragma unroll
        for (int rt = 0; rt < 4; ++rt) {
            lgt[rt][reg] = fmaf(acc[rt][reg], invT[reg], b_[rt]);
            m = fmaxf(m, lgt[rt][reg]);
        }
        mx[reg] = m;
    }
    #pragma unroll
    for (int msk = 1; msk < 16; msk <<= 1) {
        #pragma unroll
        for (int reg = 0; reg < 4; ++reg) mx[reg] = fmaxf(mx[reg], __shfl_xor(mx[reg], msk));
    }
    float ex[4][4], sm[4] = {0.f, 0.f, 0.f, 0.f};
    #pragma unroll
    for (int rt = 0; rt < 4; ++rt) {
        #pragma unroll
        for (int reg = 0; reg < 4; ++reg) {
            ex[rt][reg] = __expf(lgt[rt][reg] - mx[reg]);
            sm[reg] += ex[rt][reg];
        }
    }
    #pragma unroll
    for (int msk = 1; msk < 16; msk <<= 1) {
        #pragma unroll
        for (int reg = 0; reg < 4; ++reg) sm[reg] += __shfl_xor(sm[reg], msk);
    }

    float rsm[4];
    #pragma unroll
    for (int reg = 0; reg < 4; ++reg) {
        const bool vt = (t0w + (lg << 2) + reg) < TT;
        rsm[reg] = vt ? (1.0f / sm[reg]) : 0.f;
    }

    // ---- per-block partial asum: pa[rt] holds kr = rt*16+lr ----
    float pa[4];
    #pragma unroll
    for (int rt = 0; rt < 4; ++rt) {
        pa[rt] = ex[rt][0]*rsm[0] + ex[rt][1]*rsm[1] + ex[rt][2]*rsm[2] + ex[rt][3]*rsm[3];
        pa[rt] += __shfl_xor(pa[rt], 16);
        pa[rt] += __shfl_xor(pa[rt], 32);
    }
    // LDS layout after K loop (Wl free): Abuf = 8 waves x 64kr x 24t ushorts
    // (24.6 KB), asum partials as float[8][64] at ushort offset 12288 (24 KB).
    unsigned short* lbase = &Wl[0][0];
    float* asum_lds = reinterpret_cast<float*>(lbase + 12288);
    if (lane < 16) {
        #pragma unroll
        for (int rt = 0; rt < 4; ++rt)
            asum_lds[(w << 6) + rt*16 + lane] = pa[rt];
    }

    // ---- a' = softmax * inv_norm, transposed via LDS ----
    unsigned short* Abuf = lbase + (size_t)w * KR * 24;
    #pragma unroll
    for (int reg = 0; reg < 4; ++reg) {
        const int trow = (lg << 2) + reg;
        const float scale = invT[reg] * rsm[reg];
        #pragma unroll
        for (int rt = 0; rt < 4; ++rt)
            Abuf[(rt*16 + lr)*24 + trow] = f2bf(ex[rt][reg] * scale);
    }
    __syncthreads();

    if (tid < 64) {
        float s = 0.f;
        #pragma unroll
        for (int wv = 0; wv < 8; ++wv) s += asum_lds[(wv << 6) + tid];
        ws_asum[(size_t)blockIdx.x * 64 + tid] = s;
    }

    {
        ushort8 r0 = *reinterpret_cast<const ushort8*>(&Abuf[lane * 24]);
        ushort8 r1 = *reinterpret_cast<const ushort8*>(&Abuf[lane * 24 + 8]);
        unsigned short* dst = ws_a + ((size_t)n * KR + lane) * TP + t0w;
        *reinterpret_cast<ushort8*>(dst)     = r0;
        *reinterpret_cast<ushort8*>(dst + 8) = r1;
    }
}

// ---------------------------------------------------------------------------
// Kernel 2: GEMM2 (VLAD): grid = n x 12 c-tiles (64 c) = 768 blocks, 4 waves,
// wave tile 64kr x 16c. No LDS staging; named-variable ping-pong prefetch.
// ---------------------------------------------------------------------------
#define LOADA(d0,d1,d2,d3,t0_)                                                   \
    d0 = *reinterpret_cast<const bf16x8*>(abase +            (size_t)(t0_));     \
    d1 = *reinterpret_cast<const bf16x8*>(abase + 16*TP +    (size_t)(t0_));     \
    d2 = *reinterpret_cast<const bf16x8*>(abase + 32*TP +    (size_t)(t0_));     \
    d3 = *reinterpret_cast<const bf16x8*>(abase + 48*TP +    (size_t)(t0_));

#define LOADB(d,t0_) do {                                                        \
    const int tb2_ = (t0_) + (lg << 3);                                          \
    if ((t0_) + 32 <= TT) {                                                      \
        _Pragma("unroll")                                                        \
        for (int j_ = 0; j_ < 8; ++j_)                                           \
            ((unsigned short*)&(d))[j_] = f2bf(gb[(size_t)(tb2_ + j_) * CCH]);   \
    } else {                                                                     \
        _Pragma("unroll")                                                        \
        for (int j_ = 0; j_ < 8; ++j_) {                                         \
            float v_ = (tb2_ + j_ < TT) ? gb[(size_t)(tb2_ + j_) * CCH] : 0.f;   \
            ((unsigned short*)&(d))[j_] = f2bf(v_);                              \
        }                                                                        \
    } } while (0)

__global__ __launch_bounds__(256) void k_vlad(
    const float* __restrict__ grids,
    const unsigned short* __restrict__ ws_a,
    const float* __restrict__ ws_asum,
    const float* __restrict__ centroids,
    float* __restrict__ out)
{
    __shared__ float asum_s[64];

    const int tid  = threadIdx.x;
    const int lane = tid & 63;
    const int w    = tid >> 6;
    const int n    = blockIdx.x / 12;
    const int c0   = (blockIdx.x - n * 12) << 6;
    const int lr   = lane & 15;
    const int lg   = lane >> 4;

    if (tid < 64) {
        float s = 0.f;
        #pragma unroll
        for (int b = 0; b < 5; ++b)
            s += ws_asum[((size_t)n * 5 + b) * 64 + tid];
        asum_s[tid] = s;
    }
    __syncthreads();

    const int c = c0 + (w << 4) + lr;
    const unsigned short* abase = ws_a + ((size_t)n * KR + lr) * TP + (lg << 3);
    const float* gb = grids + (size_t)n * TT * CCH + c;

    f32x4 acc0 = {}, acc1 = {}, acc2 = {}, acc3 = {};
    bf16x8 a0, a1, a2, a3, b0;
    bf16x8 p0, p1, p2, p3, q0;

    LOADA(a0, a1, a2, a3, 0)
    LOADB(b0, 0);

    int t0 = 0;
    while (true) {
        int tn = t0 + 32;
        if (tn < TT) { LOADA(p0, p1, p2, p3, tn) LOADB(q0, tn); }
        acc0 = __builtin_amdgcn_mfma_f32_16x16x32_bf16(a0, b0, acc0, 0, 0, 0);
        acc1 = __builtin_amdgcn_mfma_f32_16x16x32_bf16(a1, b0, acc1, 0, 0, 0);
        acc2 = __builtin_amdgcn_mfma_f32_16x16x32_bf16(a2, b0, acc2, 0, 0, 0);
        acc3 = __builtin_amdgcn_mfma_f32_16x16x32_bf16(a3, b0, acc3, 0, 0, 0);
        t0 = tn;
        if (t0 >= TT) break;

        tn = t0 + 32;
        if (tn < TT) { LOADA(a0, a1, a2, a3, tn) LOADB(b0, tn); }
        acc0 = __builtin_amdgcn_mfma_f32_16x16x32_bf16(p0, q0, acc0, 0, 0, 0);
        acc1 = __builtin_amdgcn_mfma_f32_16x16x32_bf16(p1, q0, acc1, 0, 0, 0);
        acc2 = __builtin_amdgcn_mfma_f32_16x16x32_bf16(p2, q0, acc2, 0, 0, 0);
        acc3 = __builtin_amdgcn_mfma_f32_16x16x32_bf16(p3, q0, acc3, 0, 0, 0);
        t0 = tn;
        if (t0 >= TT) break;
    }

    // ---- epilogue: subtract asum*centroid, write fp32 ----
    #pragma unroll
    for (int reg = 0; reg < 4; ++reg) {
        {
            const int kr = 0*16 + (lg << 2) + reg;
            out[((size_t)n * KR + kr) * CCH + c] =
                acc0[reg] - asum_s[kr] * centroids[(size_t)kr * CCH + c];
        }
        {
            const int kr = 1*16 + (lg << 2) + reg;
            out[((size_t)n * KR + kr) * CCH + c] =
                acc1[reg] - asum_s[kr] * centroids[(size_t)kr * CCH + c];
        }
        {
            const int kr = 2*16 + (lg << 2) + reg;
            out[((size_t)n * KR + kr) * CCH + c] =
                acc2[reg] - asum_s[kr] * centroids[(size_t)kr * CCH + c];
        }
        {
            const int kr = 3*16 + (lg << 2) + reg;
            out[((size_t)n * KR + kr) * CCH + c] =
                acc3[reg] - asum_s[kr] * centroids[(size_t)kr * CCH + c];
        }
    }
}

// ---------------------------------------------------------------------------
// Kernel 3: 4 rows per 256-thr block; each 64-lane wave normalizes one
// (n,kr) row; global L2 norm of 64 unit rows = 8 exactly.
// ---------------------------------------------------------------------------
__global__ __launch_bounds__(256) void kc_norm_kernel(float* __restrict__ out)
{
    const int tid = threadIdx.x;
    const int sub = tid >> 6;
    const int l   = tid & 63;
    float4* p = reinterpret_cast<float4*>(out) + ((size_t)blockIdx.x * 4 + sub) * 192;
    float4 v0 = p[l];
    float4 v1 = p[l + 64];
    float4 v2 = p[l + 128];
    float ss = v0.x*v0.x + v0.y*v0.y + v0.z*v0.z + v0.w*v0.w
             + v1.x*v1.x + v1.y*v1.y + v1.z*v1.z + v1.w*v1.w
             + v2.x*v2.x + v2.y*v2.y + v2.z*v2.z + v2.w*v2.w;
    #pragma unroll
    for (int m = 1; m < 64; m <<= 1) ss += __shfl_xor(ss, m);
    const float sc = 0.125f / fmaxf(sqrtf(ss), EPSF);
    v0.x*=sc; v0.y*=sc; v0.z*=sc; v0.w*=sc;
    v1.x*=sc; v1.y*=sc; v1.z*=sc; v1.w*=sc;
    v2.x*=sc; v2.y*=sc; v2.z*=sc; v2.w*=sc;
    p[l] = v0;
    p[l + 64] = v1;
    p[l + 128] = v2;
}

extern "C" void kernel_launch(void* const* d_in, const int* in_sizes, int n_in,
                              void* d_out, int out_size, void* d_ws, size_t ws_size,
                              hipStream_t stream)
{
    const float* grids     = (const float*)d_in[0];
    const float* conv_w    = (const float*)d_in[1];
    const float* conv_b    = (const float*)d_in[2];
    const float* centroids = (const float*)d_in[3];
    float* out = (float*)d_out;

    unsigned short* ws_a = (unsigned short*)d_ws;                       // 64*64*640*2 = 5.24 MB
    float* ws_asum = (float*)((char*)d_ws + (size_t)NB * KR * TP * 2);  // 64*5*64*4 = 80 KB

    hipLaunchKernelGGL(k_logits, dim3(NB * 5), dim3(512), 0, stream,
                       grids, conv_w, conv_b, ws_a, ws_asum);
    hipLaunchKernelGGL(k_vlad, dim3(NB * 12), dim3(256), 0, stream,
                       grids, ws_a, ws_asum, centroids, out);
    hipLaunchKernelGGL(kc_norm_kernel, dim3(NB * KR / 4), dim3(256), 0, stream, out);
}